// Round 4
// baseline (169.680 us; speedup 1.0000x reference)
//
#include <hip/hip_runtime.h>

constexpr int Bn = 65536;   // rows (entity pairs)
constexpr int Cn = 512;     // relation classes

#define L2E 1.4426950408889634f
#define LN2 0.6931471805599453f

// One row per 16-lane group. Each lane loads 8 strided float4 chunks of
// logits + 8 of labels into explicit register arrays (all 16 loads issued
// before any compute -- sched_barrier fence), then computes and does a
// single 4-step butterfly per row.
__global__ __launch_bounds__(256) void matloss_main(
    const float* __restrict__ logits,
    const float* __restrict__ labels,
    double* __restrict__ acc) {

  const int t   = blockIdx.x * 256 + threadIdx.x;
  const int row = t >> 4;                       // 16 lanes per row
  const int o   = t & 15;                       // lane within group

  const float4* lg = reinterpret_cast<const float4*>(logits + (size_t)row * Cn);
  const float4* lb = reinterpret_cast<const float4*>(labels + (size_t)row * Cn);

  // ---- load phase: 16 independent float4 loads, all in flight ----
  float4 X[8], L[8];
#pragma unroll
  for (int j = 0; j < 8; ++j) X[j] = lg[16 * j + o];   // 256B contiguous per 16-lane group
#pragma unroll
  for (int j = 0; j < 8; ++j) L[j] = lb[16 * j + o];
  __builtin_amdgcn_sched_barrier(0);            // loads stay above, compute below

  // p   = prod over positives of (1 + exp(-|x|))   (one log per row later)
  // pm  = sum  over positives of min(x, 0)
  // s   = sum  over negatives of exp(x)            (no-max LSE: |x| < ~6)
  // cnt = number of positives
  float x0 = X[0].x;                            // logits[row,0] lives in o==0
  if (o == 0) L[0].x = 0.f;                     // threshold class: label forced 0

  float p = 1.f, s = 0.f, pm = 0.f, cnt = 0.f;
#pragma unroll
  for (int j = 0; j < 8; ++j) {
    float x[4] = {X[j].x, X[j].y, X[j].z, X[j].w};
    float l[4] = {L[j].x, L[j].y, L[j].z, L[j].w};
#pragma unroll
    for (int k = 0; k < 4; ++k) {
      bool  pos = (l[k] != 0.f);
      float sel = pos ? -fabsf(x[k]) : x[k];
      float e   = __builtin_amdgcn_exp2f(sel * L2E);
      p   *= fmaf(l[k], e, 1.f);
      s   += pos ? 0.f : e;
      pm   = fmaf(l[k], fminf(x[k], 0.f), pm);
      cnt += l[k];
    }
  }

  // 4-step butterfly within the 16-lane group
#pragma unroll
  for (int off = 1; off < 16; off <<= 1) {
    s   += __shfl_xor(s,   off);
    cnt += __shfl_xor(cnt, off);
    pm  += __shfl_xor(pm,  off);
    p   *= __shfl_xor(p,   off);
  }

  float a_term = 0.f, a_cnt = 0.f, a_l2 = 0.f;
  if (o == 0) {                                 // row finalize on group leader
    a_l2 = LN2 * __builtin_amdgcn_logf(s) - x0; // lse - x0
    if (cnt > 0.f) {
      float t0  = __builtin_amdgcn_exp2f(-fabsf(x0) * L2E);
      float ls0 = fminf(-x0, 0.f) - LN2 * __builtin_amdgcn_logf(1.f + t0);
      a_term = ls0 + pm - LN2 * __builtin_amdgcn_logf(p);
      a_cnt  = 1.f + cnt;
    }
  }

  // once-per-kernel wave reduce, then block reduce, then 3 atomics
#pragma unroll
  for (int off = 1; off < 64; off <<= 1) {
    a_term += __shfl_xor(a_term, off);
    a_cnt  += __shfl_xor(a_cnt,  off);
    a_l2   += __shfl_xor(a_l2,   off);
  }
  __shared__ float sm[3][4];
  const int lane = threadIdx.x & 63, wib = threadIdx.x >> 6;
  if (lane == 0) { sm[0][wib] = a_term; sm[1][wib] = a_cnt; sm[2][wib] = a_l2; }
  __syncthreads();
  if (threadIdx.x == 0) {
    atomicAdd(&acc[0], (double)(sm[0][0] + sm[0][1] + sm[0][2] + sm[0][3]));
    atomicAdd(&acc[1], (double)(sm[1][0] + sm[1][1] + sm[1][2] + sm[1][3]));
    atomicAdd(&acc[2], (double)(sm[2][0] + sm[2][1] + sm[2][2] + sm[2][3]));
  }
}

__global__ void matloss_final(const double* __restrict__ acc, float* __restrict__ out) {
  out[0] = (float)(-acc[0] / acc[1] + acc[2] / (double)Bn);
}

extern "C" void kernel_launch(void* const* d_in, const int* in_sizes, int n_in,
                              void* d_out, int out_size, void* d_ws, size_t ws_size,
                              hipStream_t stream) {
  const float* logits = (const float*)d_in[0];
  const float* labels = (const float*)d_in[1];
  float* out = (float*)d_out;
  double* acc = (double*)d_ws;

  hipMemsetAsync(d_ws, 0, 3 * sizeof(double), stream);  // zero accumulators (capture-safe)
  matloss_main<<<(Bn * 16) / 256, 256, 0, stream>>>(logits, labels, acc);
  matloss_final<<<1, 1, 0, stream>>>(acc, out);
}

// Round 5
// 105.641 us; speedup vs baseline: 1.6062x; 1.6062x over previous
//
#include <hip/hip_runtime.h>

constexpr int Bn = 65536;   // rows (entity pairs)
constexpr int Cn = 512;     // relation classes

#define L2E 1.4426950408889634f
#define LN2 0.6931471805599453f

typedef float f32x4 __attribute__((ext_vector_type(4)));

// One row per wave, 8 rows per wave via stride-8192 loop. All loads are
// nontemporal (bypass L2/L3 -- data is read-once, and the 268MB input set
// thrashes the 256MB L3 otherwise). Software-pipelined one row deep: the
// next row's 4 loads are issued before the current row's compute+butterfly,
// keeping 4KB/wave in flight continuously.
__global__ __launch_bounds__(256) void matloss_main(
    const float* __restrict__ logits,
    const float* __restrict__ labels,
    double* __restrict__ acc) {

  const int lane = threadIdx.x & 63;
  const int wib  = threadIdx.x >> 6;
  const int gw   = blockIdx.x * 4 + wib;        // 8192 waves, one row each per iter
  constexpr int NW = 8192;

  float a_term = 0.f, a_cnt = 0.f, a_l2 = 0.f;

  // prefetch row 0
  const f32x4* lg = reinterpret_cast<const f32x4*>(logits + (size_t)gw * Cn);
  const f32x4* lb = reinterpret_cast<const f32x4*>(labels + (size_t)gw * Cn);
  f32x4 xa = __builtin_nontemporal_load(lg + lane);
  f32x4 xb = __builtin_nontemporal_load(lg + lane + 64);
  f32x4 la = __builtin_nontemporal_load(lb + lane);
  f32x4 lc = __builtin_nontemporal_load(lb + lane + 64);

#pragma unroll
  for (int i = 0; i < 8; ++i) {
    // current row's data
    f32x4 cx0 = xa, cx1 = xb, cl0 = la, cl1 = lc;
    // issue next row's loads NOW (independent -> stay in flight under compute)
    if (i < 7) {
      const int nrow = gw + (i + 1) * NW;
      const f32x4* nlg = reinterpret_cast<const f32x4*>(logits + (size_t)nrow * Cn);
      const f32x4* nlb = reinterpret_cast<const f32x4*>(labels + (size_t)nrow * Cn);
      xa = __builtin_nontemporal_load(nlg + lane);
      xb = __builtin_nontemporal_load(nlg + lane + 64);
      la = __builtin_nontemporal_load(nlb + lane);
      lc = __builtin_nontemporal_load(nlb + lane + 64);
    }

    float x[8] = {cx0.x, cx0.y, cx0.z, cx0.w, cx1.x, cx1.y, cx1.z, cx1.w};
    float l[8] = {cl0.x, cl0.y, cl0.z, cl0.w, cl1.x, cl1.y, cl1.z, cl1.w};
    if (lane == 0) l[0] = 0.f;                  // threshold class: label forced to 0

    // p   = prod over positives of (1 + exp(-|x|))   (one log per row)
    // pm  = sum  over positives of min(x, 0)
    // s   = sum  over negatives of exp(x)            (no-max LSE: |x| < ~6)
    // cnt = number of positives
    float p = 1.f, s = 0.f, pm = 0.f, cnt = 0.f;
#pragma unroll
    for (int j = 0; j < 8; ++j) {
      bool  pos = (l[j] != 0.f);
      float sel = pos ? -fabsf(x[j]) : x[j];
      float e   = __builtin_amdgcn_exp2f(sel * L2E);
      p   *= fmaf(l[j], e, 1.f);
      s   += pos ? 0.f : e;
      pm   = fmaf(l[j], fminf(x[j], 0.f), pm);
      cnt += l[j];
    }
    // 6-step butterfly, 4 independent chains
#pragma unroll
    for (int off = 32; off; off >>= 1) {
      s   += __shfl_xor(s,   off);
      cnt += __shfl_xor(cnt, off);
      pm  += __shfl_xor(pm,  off);
      p   *= __shfl_xor(p,   off);
    }
    float x0 = __shfl(x[0], 0);                 // logits[row, 0]

    a_l2 += LN2 * __builtin_amdgcn_logf(s) - x0;   // lse - x0
    if (cnt > 0.f) {                            // wave-uniform branch
      float t0  = __builtin_amdgcn_exp2f(-fabsf(x0) * L2E);
      float ls0 = fminf(-x0, 0.f) - LN2 * __builtin_amdgcn_logf(1.f + t0);
      a_term += ls0 + pm - LN2 * __builtin_amdgcn_logf(p);
      a_cnt  += 1.f + cnt;
    }
  }

  __shared__ float sm[3][4];
  if (lane == 0) { sm[0][wib] = a_term; sm[1][wib] = a_cnt; sm[2][wib] = a_l2; }
  __syncthreads();
  if (threadIdx.x == 0) {
    atomicAdd(&acc[0], (double)(sm[0][0] + sm[0][1] + sm[0][2] + sm[0][3]));
    atomicAdd(&acc[1], (double)(sm[1][0] + sm[1][1] + sm[1][2] + sm[1][3]));
    atomicAdd(&acc[2], (double)(sm[2][0] + sm[2][1] + sm[2][2] + sm[2][3]));
  }
}

__global__ void matloss_final(const double* __restrict__ acc, float* __restrict__ out) {
  out[0] = (float)(-acc[0] / acc[1] + acc[2] / (double)Bn);
}

extern "C" void kernel_launch(void* const* d_in, const int* in_sizes, int n_in,
                              void* d_out, int out_size, void* d_ws, size_t ws_size,
                              hipStream_t stream) {
  const float* logits = (const float*)d_in[0];
  const float* labels = (const float*)d_in[1];
  float* out = (float*)d_out;
  double* acc = (double*)d_ws;

  hipMemsetAsync(d_ws, 0, 3 * sizeof(double), stream);  // zero accumulators (capture-safe)
  matloss_main<<<2048, 256, 0, stream>>>(logits, labels, acc);
  matloss_final<<<1, 1, 0, stream>>>(acc, out);
}

// Round 6
// 104.332 us; speedup vs baseline: 1.6263x; 1.0125x over previous
//
#include <hip/hip_runtime.h>

constexpr int Bn = 65536;   // rows (entity pairs)
constexpr int Cn = 512;     // relation classes

#define L2E 1.4426950408889634f
#define LN2 0.6931471805599453f

typedef float f32x4 __attribute__((ext_vector_type(4)));

// One row per wave, 8 rows per wave (stride 8192). 2-deep static prefetch
// pipeline; per-row partials kept in registers and ALL cross-lane reductions
// deferred to a single batched butterfly phase after the loop, so the hot
// loop is pure {global_load x4, ~80 VALU}. __launch_bounds__(256,4) lifts
// the VGPR cap to 128 so the allocator cannot serialize the prefetch.
__global__ __launch_bounds__(256, 4) void matloss_main(
    const float* __restrict__ logits,
    const float* __restrict__ labels,
    double* __restrict__ acc) {

  const int lane = threadIdx.x & 63;
  const int wib  = threadIdx.x >> 6;
  const int gw   = blockIdx.x * 4 + wib;        // 8192 waves
  constexpr int NW = 8192;                      // row stride between iterations
  constexpr int R  = 8;                         // rows per wave

  const f32x4* lgp = reinterpret_cast<const f32x4*>(logits);
  const f32x4* lbp = reinterpret_cast<const f32x4*>(labels);

  auto issue = [&](int i, f32x4& xa, f32x4& xb, f32x4& la, f32x4& lc) {
    size_t off = (size_t)(gw + i * NW) * (Cn / 4);
    xa = __builtin_nontemporal_load(lgp + off + lane);
    xb = __builtin_nontemporal_load(lgp + off + lane + 64);
    la = __builtin_nontemporal_load(lbp + off + lane);
    lc = __builtin_nontemporal_load(lbp + off + lane + 64);
  };

  f32x4 xa0, xb0, la0, lc0, xa1, xb1, la1, lc1;
  issue(0, xa0, xb0, la0, lc0);                 // prefetch rows 0,1
  issue(1, xa1, xb1, la1, lc1);

  // per-row lane partials (reduced across the wave AFTER the loop)
  float s[R], p[R], pm[R], cnt[R], x0v[R];

#pragma unroll
  for (int i = 0; i < R; ++i) {
    f32x4 xa, xb, la, lc;
    if ((i & 1) == 0) { xa = xa0; xb = xb0; la = la0; lc = lc0; }
    else              { xa = xa1; xb = xb1; la = la1; lc = lc1; }
    if (i + 2 < R) {                            // refill the buffer just drained
      if ((i & 1) == 0) issue(i + 2, xa0, xb0, la0, lc0);
      else              issue(i + 2, xa1, xb1, la1, lc1);
    }

    float x[8] = {xa.x, xa.y, xa.z, xa.w, xb.x, xb.y, xb.z, xb.w};
    float l[8] = {la.x, la.y, la.z, la.w, lc.x, lc.y, lc.z, lc.w};
    if (lane == 0) l[0] = 0.f;                  // threshold class: label forced 0
    x0v[i] = x[0];                              // lane 0 holds logits[row,0]

    // P  = prod over positives of (1 + exp(-|x|))   (one log per row later)
    // PM = sum  over positives of min(x, 0)
    // S  = sum  over negatives of exp(x)            (no-max LSE: |x| < ~6)
    float P = 1.f, S = 0.f, PM = 0.f, CN = 0.f;
#pragma unroll
    for (int k = 0; k < 8; ++k) {
      bool  pos = (l[k] != 0.f);
      float sel = pos ? -fabsf(x[k]) : x[k];
      float e   = __builtin_amdgcn_exp2f(sel * L2E);
      P  *= fmaf(l[k], e, 1.f);
      S  += pos ? 0.f : e;
      PM  = fmaf(l[k], fminf(x[k], 0.f), PM);
      CN += l[k];
    }
    s[i] = S; p[i] = P; pm[i] = PM; cnt[i] = CN;
  }

  // batched butterflies: 8 rows x 4 chains = 32 independent DS chains/step
#pragma unroll
  for (int off = 1; off < 64; off <<= 1) {
#pragma unroll
    for (int i = 0; i < R; ++i) {
      s[i]   += __shfl_xor(s[i],   off);
      cnt[i] += __shfl_xor(cnt[i], off);
      pm[i]  += __shfl_xor(pm[i],  off);
      p[i]   *= __shfl_xor(p[i],   off);
    }
  }

  float a_term = 0.f, a_cnt = 0.f, a_l2 = 0.f;
#pragma unroll
  for (int i = 0; i < R; ++i) {
    float x0 = __shfl(x0v[i], 0);
    a_l2 += LN2 * __builtin_amdgcn_logf(s[i]) - x0;      // lse - x0
    if (cnt[i] > 0.f) {                                  // wave-uniform
      float t0  = __builtin_amdgcn_exp2f(-fabsf(x0) * L2E);
      float ls0 = fminf(-x0, 0.f) - LN2 * __builtin_amdgcn_logf(1.f + t0);
      a_term += ls0 + pm[i] - LN2 * __builtin_amdgcn_logf(p[i]);
      a_cnt  += 1.f + cnt[i];
    }
  }

  __shared__ float sm[3][4];
  if (lane == 0) { sm[0][wib] = a_term; sm[1][wib] = a_cnt; sm[2][wib] = a_l2; }
  __syncthreads();
  if (threadIdx.x == 0) {
    atomicAdd(&acc[0], (double)(sm[0][0] + sm[0][1] + sm[0][2] + sm[0][3]));
    atomicAdd(&acc[1], (double)(sm[1][0] + sm[1][1] + sm[1][2] + sm[1][3]));
    atomicAdd(&acc[2], (double)(sm[2][0] + sm[2][1] + sm[2][2] + sm[2][3]));
  }
}

__global__ void matloss_final(const double* __restrict__ acc, float* __restrict__ out) {
  out[0] = (float)(-acc[0] / acc[1] + acc[2] / (double)Bn);
}

extern "C" void kernel_launch(void* const* d_in, const int* in_sizes, int n_in,
                              void* d_out, int out_size, void* d_ws, size_t ws_size,
                              hipStream_t stream) {
  const float* logits = (const float*)d_in[0];
  const float* labels = (const float*)d_in[1];
  float* out = (float*)d_out;
  double* acc = (double*)d_ws;

  hipMemsetAsync(d_ws, 0, 3 * sizeof(double), stream);  // zero accumulators (capture-safe)
  matloss_main<<<2048, 256, 0, stream>>>(logits, labels, acc);
  matloss_final<<<1, 1, 0, stream>>>(acc, out);
}

// Round 7
// 98.620 us; speedup vs baseline: 1.7205x; 1.0579x over previous
//
#include <hip/hip_runtime.h>

constexpr int Bn = 65536;   // rows (entity pairs)
constexpr int Cn = 512;     // relation classes

#define L2E 1.4426950408889634f
#define LN2 0.6931471805599453f

typedef float f32x4 __attribute__((ext_vector_type(4)));

// Issue one row's 4 loads (logits lo/hi, labels lo/hi) as raw asm so the
// compiler cannot sink them to their use. Results land asynchronously;
// consumption is gated by hand-counted s_waitcnt vmcnt(N).
__device__ __forceinline__ void issue_row(const float* lg_row, const float* lb_row,
                                          int lane,
                                          f32x4& xa, f32x4& xb, f32x4& la, f32x4& lc) {
  const float* ga = lg_row + lane * 4;          // +lane*16 bytes; hi half at +1024B
  const float* gb = lb_row + lane * 4;
  asm volatile("global_load_dwordx4 %0, %2, off\n\t"
               "global_load_dwordx4 %1, %2, off offset:1024"
               : "=&v"(xa), "=&v"(xb) : "v"(ga));
  asm volatile("global_load_dwordx4 %0, %2, off\n\t"
               "global_load_dwordx4 %1, %2, off offset:1024"
               : "=&v"(la), "=&v"(lc) : "v"(gb));
}

// One row per wave per step, 8 rows per wave (stride 8192). 3-row-deep
// software pipeline with inline-asm loads + counted vmcnt: 12 loads (12KB)
// per wave stay in flight across each row's compute+butterfly.
__global__ __launch_bounds__(256, 4) void matloss_main(
    const float* __restrict__ logits,
    const float* __restrict__ labels,
    double* __restrict__ acc) {

  const int lane = threadIdx.x & 63;
  const int wib  = threadIdx.x >> 6;
  const int gw   = blockIdx.x * 4 + wib;        // 8192 waves, fully resident
  constexpr int NW = 8192;                      // row stride between iterations
  constexpr int R  = 8;                         // rows per wave
  constexpr int D  = 3;                         // pipeline depth

  f32x4 XA[D], XB[D], LA[D], LC[D];             // indices compile-time after unroll

#pragma unroll
  for (int i = 0; i < D; ++i)                   // prologue: rows 0,1,2 in flight (12 loads)
    issue_row(logits + (size_t)(gw + i * NW) * Cn,
              labels + (size_t)(gw + i * NW) * Cn, lane,
              XA[i], XB[i], LA[i], LC[i]);

  float a_term = 0.f, a_cnt = 0.f, a_l2 = 0.f;

#pragma unroll
  for (int i = 0; i < R; ++i) {
    // wait for row i's 4 loads: outstanding drops to {8,8,8,8,8,8,4,0}
    if (i < R - 2)       asm volatile("s_waitcnt vmcnt(8)" ::: "memory");
    else if (i == R - 2) asm volatile("s_waitcnt vmcnt(4)" ::: "memory");
    else                 asm volatile("s_waitcnt vmcnt(0)" ::: "memory");
    __builtin_amdgcn_sched_barrier(0);          // rule #18: no consumer hoisting

    const int b = i % D;
    float x[8] = {XA[b].x, XA[b].y, XA[b].z, XA[b].w,
                  XB[b].x, XB[b].y, XB[b].z, XB[b].w};
    float l[8] = {LA[b].x, LA[b].y, LA[b].z, LA[b].w,
                  LC[b].x, LC[b].y, LC[b].z, LC[b].w};

    // refill the slot just drained: row i+3 goes in flight under this compute
    if (i + D < R)
      issue_row(logits + (size_t)(gw + (i + D) * NW) * Cn,
                labels + (size_t)(gw + (i + D) * NW) * Cn, lane,
                XA[b], XB[b], LA[b], LC[b]);

    if (lane == 0) l[0] = 0.f;                  // threshold class: label forced 0

    // P  = prod over positives of (1 + exp(-|x|))   (one log per row)
    // PM = sum  over positives of min(x, 0)
    // S  = sum  over negatives of exp(x)            (no-max LSE: |x| < ~6)
    float P = 1.f, S = 0.f, PM = 0.f, CN = 0.f;
#pragma unroll
    for (int k = 0; k < 8; ++k) {
      bool  pos = (l[k] != 0.f);
      float sel = pos ? -fabsf(x[k]) : x[k];
      float e   = __builtin_amdgcn_exp2f(sel * L2E);
      P  *= fmaf(l[k], e, 1.f);
      S  += pos ? 0.f : e;
      PM  = fmaf(l[k], fminf(x[k], 0.f), PM);
      CN += l[k];
    }
    // 6-step butterfly (4 independent chains) -- overlaps in-flight loads
#pragma unroll
    for (int off = 32; off; off >>= 1) {
      S  += __shfl_xor(S,  off);
      CN += __shfl_xor(CN, off);
      PM += __shfl_xor(PM, off);
      P  *= __shfl_xor(P,  off);
    }
    float x0 = __shfl(x[0], 0);                 // logits[row, 0]

    a_l2 += LN2 * __builtin_amdgcn_logf(S) - x0;   // lse - x0
    if (CN > 0.f) {                             // wave-uniform branch
      float t0  = __builtin_amdgcn_exp2f(-fabsf(x0) * L2E);
      float ls0 = fminf(-x0, 0.f) - LN2 * __builtin_amdgcn_logf(1.f + t0);
      a_term += ls0 + PM - LN2 * __builtin_amdgcn_logf(P);
      a_cnt  += 1.f + CN;
    }
  }

  __shared__ float sm[3][4];
  if (lane == 0) { sm[0][wib] = a_term; sm[1][wib] = a_cnt; sm[2][wib] = a_l2; }
  __syncthreads();
  if (threadIdx.x == 0) {
    atomicAdd(&acc[0], (double)(sm[0][0] + sm[0][1] + sm[0][2] + sm[0][3]));
    atomicAdd(&acc[1], (double)(sm[1][0] + sm[1][1] + sm[1][2] + sm[1][3]));
    atomicAdd(&acc[2], (double)(sm[2][0] + sm[2][1] + sm[2][2] + sm[2][3]));
  }
}

__global__ void matloss_final(const double* __restrict__ acc, float* __restrict__ out) {
  out[0] = (float)(-acc[0] / acc[1] + acc[2] / (double)Bn);
}

extern "C" void kernel_launch(void* const* d_in, const int* in_sizes, int n_in,
                              void* d_out, int out_size, void* d_ws, size_t ws_size,
                              hipStream_t stream) {
  const float* logits = (const float*)d_in[0];
  const float* labels = (const float*)d_in[1];
  float* out = (float*)d_out;
  double* acc = (double*)d_ws;

  hipMemsetAsync(d_ws, 0, 3 * sizeof(double), stream);  // zero accumulators (capture-safe)
  matloss_main<<<2048, 256, 0, stream>>>(logits, labels, acc);
  matloss_final<<<1, 1, 0, stream>>>(acc, out);
}

// Round 8
// 75.591 us; speedup vs baseline: 2.2447x; 1.3046x over previous
//
#include <hip/hip_runtime.h>

constexpr int Bn = 65536;   // rows (entity pairs)
constexpr int Cn = 512;     // relation classes

#define L2E 1.4426950408889634f
#define LN2 0.6931471805599453f

typedef float f32x4 __attribute__((ext_vector_type(4)));

// Global->LDS DMA: no VGPR destination, so the register allocator cannot
// serialize the pipeline. HW scatters lane l's 16B to ldsptr + l*16.
__device__ __forceinline__ void gl2lds16(const float* g, float* l) {
  __builtin_amdgcn_global_load_lds(
      (const __attribute__((address_space(1))) void*)g,
      (__attribute__((address_space(3))) void*)l, 16, 0, 0);
}

__device__ __forceinline__ uint32_t lds_addr(const void* p) {
  return (uint32_t)(uintptr_t)(__attribute__((address_space(3))) const char*)(const char*)p;
}

// One row per wave, 16 rows/wave (stride 4096). Double-buffered LDS slots
// (4KB = one row's logits lo/hi + labels lo/hi), staged via global_load_lds
// with hand-counted vmcnt(4) so 8 loads (8KB) per wave stay in flight.
// 1024 blocks x 4 waves, 32.8KB LDS -> exactly 4 blocks/CU, one generation.
__global__ __launch_bounds__(256, 4) void matloss_main(
    const float* __restrict__ logits,
    const float* __restrict__ labels,
    double* __restrict__ acc) {

  const int lane = threadIdx.x & 63;
  const int wib  = threadIdx.x >> 6;
  const int gw   = blockIdx.x * 4 + wib;        // 4096 waves, all resident
  constexpr int NW = 4096;                      // row stride between iterations
  constexpr int R  = 16;                        // rows per wave

  __shared__ float smem[4 * 2 * 1024];          // [wave][slot][1024 floats]
  float* slot0 = &smem[wib * 2048];             // slot: lg[0..255],lg[256..511],
  float* slot1 = slot0 + 1024;                  //       lb[0..255],lb[256..511]

  auto stage = [&](int i, float* slot) {        // 4 vmem ops, 4KB, zero VGPRs
    const float* gl = logits + (size_t)(gw + i * NW) * Cn + lane * 4;
    const float* gb = labels + (size_t)(gw + i * NW) * Cn + lane * 4;
    gl2lds16(gl,       slot);
    gl2lds16(gl + 256, slot + 256);
    gl2lds16(gb,       slot + 512);
    gl2lds16(gb + 256, slot + 768);
  };

  stage(0, slot0);                              // prologue: 8 loads in flight
  stage(1, slot1);

  const uint32_t a0 = lds_addr(slot0) + lane * 16;
  const uint32_t a1 = lds_addr(slot1) + lane * 16;

  float a_term = 0.f, a_cnt = 0.f, a_l2 = 0.f;

#pragma unroll
  for (int i = 0; i < R; ++i) {
    if (i == R - 1) asm volatile("s_waitcnt vmcnt(0)" ::: "memory");
    else            asm volatile("s_waitcnt vmcnt(4)" ::: "memory");  // counted, never 0
    __builtin_amdgcn_sched_barrier(0);

    f32x4 xa, xb, la, lc;
    const uint32_t va = (i & 1) ? a1 : a0;
    asm volatile("ds_read_b128 %0, %4\n\t"
                 "ds_read_b128 %1, %4 offset:1024\n\t"
                 "ds_read_b128 %2, %4 offset:2048\n\t"
                 "ds_read_b128 %3, %4 offset:3072"
                 : "=&v"(xa), "=&v"(xb), "=&v"(la), "=&v"(lc)
                 : "v"(va));
    asm volatile("s_waitcnt lgkmcnt(0)" ::: "memory");
    __builtin_amdgcn_sched_barrier(0);          // rule #18: no consumer hoisting

    if (i + 2 < R) stage(i + 2, (i & 1) ? slot1 : slot0);  // refill under compute

    float x[8] = {xa.x, xa.y, xa.z, xa.w, xb.x, xb.y, xb.z, xb.w};
    float l[8] = {la.x, la.y, la.z, la.w, lc.x, lc.y, lc.z, lc.w};
    if (lane == 0) l[0] = 0.f;                  // threshold class: label forced 0

    // P  = prod over positives of (1 + exp(-|x|))   (one log per row)
    // PM = sum  over positives of min(x, 0)
    // S  = sum  over negatives of exp(x)            (no-max LSE: |x| < ~6)
    float P = 1.f, S = 0.f, PM = 0.f, CN = 0.f;
#pragma unroll
    for (int k = 0; k < 8; ++k) {
      bool  pos = (l[k] != 0.f);
      float sel = pos ? -fabsf(x[k]) : x[k];
      float e   = __builtin_amdgcn_exp2f(sel * L2E);
      P  *= fmaf(l[k], e, 1.f);
      S  += pos ? 0.f : e;
      PM  = fmaf(l[k], fminf(x[k], 0.f), PM);
      CN += l[k];
    }
#pragma unroll
    for (int off = 32; off; off >>= 1) {        // 6-step butterfly, 4 chains
      S  += __shfl_xor(S,  off);
      CN += __shfl_xor(CN, off);
      PM += __shfl_xor(PM, off);
      P  *= __shfl_xor(P,  off);
    }
    float x0 = __shfl(x[0], 0);                 // logits[row, 0]

    a_l2 += LN2 * __builtin_amdgcn_logf(S) - x0;   // lse - x0
    if (CN > 0.f) {                             // wave-uniform branch
      float t0  = __builtin_amdgcn_exp2f(-fabsf(x0) * L2E);
      float ls0 = fminf(-x0, 0.f) - LN2 * __builtin_amdgcn_logf(1.f + t0);
      a_term += ls0 + PM - LN2 * __builtin_amdgcn_logf(P);
      a_cnt  += 1.f + CN;
    }
  }

  __shared__ float sm[3][4];
  if (lane == 0) { sm[0][wib] = a_term; sm[1][wib] = a_cnt; sm[2][wib] = a_l2; }
  __syncthreads();
  if (threadIdx.x == 0) {
    atomicAdd(&acc[0], (double)(sm[0][0] + sm[0][1] + sm[0][2] + sm[0][3]));
    atomicAdd(&acc[1], (double)(sm[1][0] + sm[1][1] + sm[1][2] + sm[1][3]));
    atomicAdd(&acc[2], (double)(sm[2][0] + sm[2][1] + sm[2][2] + sm[2][3]));
  }
}

__global__ void matloss_final(const double* __restrict__ acc, float* __restrict__ out) {
  out[0] = (float)(-acc[0] / acc[1] + acc[2] / (double)Bn);
}

extern "C" void kernel_launch(void* const* d_in, const int* in_sizes, int n_in,
                              void* d_out, int out_size, void* d_ws, size_t ws_size,
                              hipStream_t stream) {
  const float* logits = (const float*)d_in[0];
  const float* labels = (const float*)d_in[1];
  float* out = (float*)d_out;
  double* acc = (double*)d_ws;

  hipMemsetAsync(d_ws, 0, 3 * sizeof(double), stream);  // zero accumulators (capture-safe)
  matloss_main<<<1024, 256, 0, stream>>>(logits, labels, acc);
  matloss_final<<<1, 1, 0, stream>>>(acc, out);
}